// Round 16
// baseline (186.578 us; speedup 1.0000x reference)
//
#include <hip/hip_runtime.h>

#define BS 65536
#define DIM 64
#define SD 1024
#define NTHREADS 512
#define NBLK 512          // 8 waves = 4 pairs; pair = 32 rows; halves split 1024 cbs
#define LOG2E 1.44269504f
#define LN2   0.69314718f

// workspace layout (bytes)
#define WS_CBB   0        // [1024][64] bf16 row-major codebook (128 KB)
#define WS_CBT   131072   // [64][1024] bf16 transposed codebook (128 KB)
#define WS_C2    262144   // [1024] f32
#define WS_AVG   266240   // [1024] f32 accumulator (zeroed by prep)
#define WS_APART 270336   // [512][1024] f32 per-block avg partials (2 MB)
#define WS_LPART 2367488  // [512] f32 per-block loss partials

typedef __attribute__((ext_vector_type(8))) short bf16x8;
typedef __attribute__((ext_vector_type(4))) short bf16x4;
typedef __attribute__((ext_vector_type(4))) float f32x4;

// K=16 bf16 MFMA: host pass only parses; device uses builtin or inline asm.
#if defined(__HIP_DEVICE_COMPILE__)
#if __has_builtin(__builtin_amdgcn_mfma_f32_16x16x16bf16_1k)
__device__ __forceinline__ f32x4 MFMA16(bf16x4 a, bf16x4 b, f32x4 c) {
  return __builtin_amdgcn_mfma_f32_16x16x16bf16_1k(a, b, c, 0, 0, 0);
}
#else
__device__ __forceinline__ f32x4 MFMA16(bf16x4 a, bf16x4 b, f32x4 c) {
  asm volatile("v_mfma_f32_16x16x16_bf16 %0, %1, %2, %0"
               : "+v"(c) : "v"(a), "v"(b));
  return c;
}
#endif
#else
__device__ __forceinline__ f32x4 MFMA16(bf16x4 a, bf16x4 b, f32x4 c) { return c; }
#endif

__device__ __forceinline__ unsigned short f2bf(float f) {
  union { float f; unsigned int u; } v; v.f = f;
  unsigned int r = v.u + 0x7fffu + ((v.u >> 16) & 1u);
  return (unsigned short)(r >> 16);
}
__device__ __forceinline__ unsigned cvtpk(float a, float b) {  // lo=bf16(a), hi=bf16(b)
  unsigned r;
  asm("v_cvt_pk_bf16_f32 %0, %1, %2" : "=v"(r) : "v"(a), "v"(b));
  return r;
}
__device__ __forceinline__ bf16x4 mk4(unsigned lo, unsigned hi) {
  union { uint2 u; bf16x4 v; } x; x.u.x = lo; x.u.y = hi; return x.v;
}
__device__ __forceinline__ float bflo(unsigned v) {
  union { unsigned u; float f; } x; x.u = v << 16; return x.f;
}
__device__ __forceinline__ float bfhi(unsigned v) {
  union { unsigned u; float f; } x; x.u = v & 0xffff0000u; return x.f;
}
__device__ __forceinline__ float wsum64(float v) {
  #pragma unroll
  for (int m = 1; m < 64; m <<= 1) v += __shfl_xor(v, m);
  return v;
}
__device__ __forceinline__ bf16x8 pack8(float4 a, float4 b) {
  bf16x8 r;
  r[0]=(short)f2bf(a.x); r[1]=(short)f2bf(a.y); r[2]=(short)f2bf(a.z); r[3]=(short)f2bf(a.w);
  r[4]=(short)f2bf(b.x); r[5]=(short)f2bf(b.y); r[6]=(short)f2bf(b.z); r[7]=(short)f2bf(b.w);
  return r;
}

// ---------------- prep: bf16 codebook (row-major + transposed), c2, zero avgg ----------------
__global__ __launch_bounds__(256) void gvq_prep(const float* __restrict__ cb, char* __restrict__ ws) {
  int gid = blockIdx.x * 256 + threadIdx.x;   // 0..16383
  int j = gid >> 4, dg = gid & 15;
  float4 v = *(const float4*)(cb + j * DIM + dg * 4);
  float s = v.x*v.x + v.y*v.y + v.z*v.z + v.w*v.w;
  s += __shfl_xor(s, 1); s += __shfl_xor(s, 2); s += __shfl_xor(s, 4); s += __shfl_xor(s, 8);
  unsigned short b0 = f2bf(v.x), b1 = f2bf(v.y), b2 = f2bf(v.z), b3 = f2bf(v.w);
  uint2 pk;
  pk.x = (unsigned)b0 | ((unsigned)b1 << 16);
  pk.y = (unsigned)b2 | ((unsigned)b3 << 16);
  *(uint2*)(ws + WS_CBB + j * 128 + dg * 8) = pk;
  unsigned short* tb = (unsigned short*)(ws + WS_CBT);
  int d = dg * 4;
  tb[(d + 0) * 1024 + j] = b0; tb[(d + 1) * 1024 + j] = b1;
  tb[(d + 2) * 1024 + j] = b2; tb[(d + 3) * 1024 + j] = b3;
  if (dg == 0) ((float*)(ws + WS_C2))[j] = s;
  if (gid < SD) ((float*)(ws + WS_AVG))[gid] = 0.f;
}

// ---------------- main: 512 blocks x 4 pairs; wave = 32 rows (2 rowgroups) x 512 cbs ----------------
__global__ __launch_bounds__(NTHREADS, 2) void gvq_main(
    const float* __restrict__ z, const float* __restrict__ pq,
    const float* __restrict__ u, char* __restrict__ ws,
    float* __restrict__ out)
{
  __shared__ float pavw[4][1024];        // per-pair avg-prob accumulator
  __shared__ char  zqm_s[4][4608];       // per-pair zq partial: 64 lanes x 72B
  __shared__ float stm[4][2][2][16];     // [pair][h][rg][row]
  __shared__ float stz[4][2][2][16];
  __shared__ float ste[4][2][2][16];
  __shared__ float zy2[4][2][2][16];
  __shared__ float wred[8];

  const int t    = threadIdx.x;
  const int lane = t & 63;
  const int wave = t >> 6;
  const int l15  = lane & 15;
  const int g    = lane >> 4;
  const int pair = wave >> 1;
  const int h    = wave & 1;
  const int r0   = blockIdx.x * 128 + pair * 32;
  const int ttB  = h * 32;

  const char*  cbbp = ws + WS_CBB;
  const char*  cbtp = ws + WS_CBT;
  const float* c2p  = (const float*)(ws + WS_C2);
  float* apart = (float*)(ws + WS_APART);
  float* lpart = (float*)(ws + WS_LPART);

  const float weight = 0.5f / fmaxf(pq[0], 1e-10f);
  const float w2  = weight * LOG2E;
  const float w22 = 2.f * w2;

  {
    float* pz = &pavw[0][0];
    #pragma unroll
    for (int i = 0; i < 8; ++i) pz[t + 512 * i] = 0.f;
  }

  // ---- z fragments for both rowgroups + z2 ----
  const float* zrA = z + (size_t)(r0 + l15) * DIM + g * 8;
  const float* zrB = zrA + 16 * DIM;
  float4 a0 = *(const float4*)(zrA),      a1 = *(const float4*)(zrA + 4);
  float4 a2 = *(const float4*)(zrA + 32), a3 = *(const float4*)(zrA + 36);
  float4 b0 = *(const float4*)(zrB),      b1 = *(const float4*)(zrB + 4);
  float4 b2 = *(const float4*)(zrB + 32), b3 = *(const float4*)(zrB + 36);
  bf16x8 zfA0 = pack8(a0, a1), zfA1 = pack8(a2, a3);
  bf16x8 zfB0 = pack8(b0, b1), zfB1 = pack8(b2, b3);
  float zsqA = a0.x*a0.x+a0.y*a0.y+a0.z*a0.z+a0.w*a0.w
             + a1.x*a1.x+a1.y*a1.y+a1.z*a1.z+a1.w*a1.w
             + a2.x*a2.x+a2.y*a2.y+a2.z*a2.z+a2.w*a2.w
             + a3.x*a3.x+a3.y*a3.y+a3.z*a3.z+a3.w*a3.w;
  float zsqB = b0.x*b0.x+b0.y*b0.y+b0.z*b0.z+b0.w*b0.w
             + b1.x*b1.x+b1.y*b1.y+b1.z*b1.z+b1.w*b1.w
             + b2.x*b2.x+b2.y*b2.y+b2.z*b2.z+b2.w*b2.w
             + b3.x*b3.x+b3.y*b3.y+b3.z*b3.z+b3.w*b3.w;
  zsqA += __shfl_xor(zsqA, 16); zsqA += __shfl_xor(zsqA, 32);
  zsqB += __shfl_xor(zsqB, 16); zsqB += __shfl_xor(zsqB, 32);
  const float zpA = w2 * zsqA;
  const float zpB = w2 * zsqB;

  // ---- pass AB: online (m, Zs, E1) per rowgroup; 2 chain-sets per rowgroup ----
  float mA0c = -1e30f, ZA0c = 0.f, EA0c = 0.f;
  float mA1c = -1e30f, ZA1c = 0.f, EA1c = 0.f;
  float mB0c = -1e30f, ZB0c = 0.f, EB0c = 0.f;
  float mB1c = -1e30f, ZB1c = 0.f, EB1c = 0.f;
#define ONLUPD(ACC, ZP, M, ZS, EV, C2V) do { \
    float s0 = fmaf(w22, ACC[0], -((ZP) + w2 * C2V.x)); \
    float s1 = fmaf(w22, ACC[1], -((ZP) + w2 * C2V.y)); \
    float s2 = fmaf(w22, ACC[2], -((ZP) + w2 * C2V.z)); \
    float s3 = fmaf(w22, ACC[3], -((ZP) + w2 * C2V.w)); \
    float nm = fmaxf(fmaxf(fmaxf(s0, s1), fmaxf(s2, s3)), M); \
    float dmx = fminf(nm - M, 60.f); \
    float sc = __builtin_amdgcn_exp2f(-dmx); \
    EV = sc * (EV - dmx * ZS); \
    ZS = sc * ZS; \
    M = nm; \
    float d0 = s0 - M, d1 = s1 - M, d2 = s2 - M, d3 = s3 - M; \
    float e0 = __builtin_amdgcn_exp2f(d0), e1 = __builtin_amdgcn_exp2f(d1); \
    float e2 = __builtin_amdgcn_exp2f(d2), e3 = __builtin_amdgcn_exp2f(d3); \
    ZS += (e0 + e1) + (e2 + e3); \
    EV += (e0 * d0 + e1 * d1) + (e2 * d2 + e3 * d3); \
  } while (0)
#define ABSTEP(TT, MA, ZSA, EVA, MB, ZSB, EVB) do { \
    const char* cp = cbbp + ((TT) * 16 + l15) * 128 + g * 16; \
    bf16x8 cf0 = *(const bf16x8*)(cp); \
    bf16x8 cf1 = *(const bf16x8*)(cp + 64); \
    float4 c2v = *(const float4*)(c2p + (TT) * 16 + g * 4); \
    f32x4 acc0 = {0.f, 0.f, 0.f, 0.f}; \
    acc0 = __builtin_amdgcn_mfma_f32_16x16x32_bf16(cf0, zfA0, acc0, 0, 0, 0); \
    acc0 = __builtin_amdgcn_mfma_f32_16x16x32_bf16(cf1, zfA1, acc0, 0, 0, 0); \
    f32x4 acc1 = {0.f, 0.f, 0.f, 0.f}; \
    acc1 = __builtin_amdgcn_mfma_f32_16x16x32_bf16(cf0, zfB0, acc1, 0, 0, 0); \
    acc1 = __builtin_amdgcn_mfma_f32_16x16x32_bf16(cf1, zfB1, acc1, 0, 0, 0); \
    ONLUPD(acc0, zpA, MA, ZSA, EVA, c2v); \
    ONLUPD(acc1, zpB, MB, ZSB, EVB, c2v); \
  } while (0)
  for (int tt = ttB; tt < ttB + 32; tt += 2) {
    ABSTEP(tt,     mA0c, ZA0c, EA0c, mB0c, ZB0c, EB0c);
    ABSTEP(tt + 1, mA1c, ZA1c, EA1c, mB1c, ZB1c, EB1c);
  }
#undef ABSTEP
#undef ONLUPD
  // merge chain-sets (all finite: each saw 16 subtiles)
  float mA, ZA, EA, mB, ZB, EB;
  {
    mA = fmaxf(mA0c, mA1c);
    float aa = __builtin_amdgcn_exp2f(mA0c - mA);
    float bb = __builtin_amdgcn_exp2f(mA1c - mA);
    ZA = aa * ZA0c + bb * ZA1c;
    EA = aa * (EA0c - (mA - mA0c) * ZA0c) + bb * (EA1c - (mA - mA1c) * ZA1c);
    mB = fmaxf(mB0c, mB1c);
    float cc = __builtin_amdgcn_exp2f(mB0c - mB);
    float dd = __builtin_amdgcn_exp2f(mB1c - mB);
    ZB = cc * ZB0c + dd * ZB1c;
    EB = cc * (EB0c - (mB - mB0c) * ZB0c) + dd * (EB1c - (mB - mB1c) * ZB1c);
  }
  // cross-g merge per rowgroup
#define MERGEG(M, ZS, EV) do { \
    _Pragma("unroll") \
    for (int mk = 16; mk < 64; mk <<= 1) { \
      float mo = __shfl_xor(M, mk); \
      float Zo = __shfl_xor(ZS, mk); \
      float Eo = __shfl_xor(EV, mk); \
      float MM = fmaxf(M, mo); \
      float aa = __builtin_amdgcn_exp2f(M - MM); \
      float bb = __builtin_amdgcn_exp2f(mo - MM); \
      EV = aa * (EV - (MM - M) * ZS) + bb * (Eo - (MM - mo) * Zo); \
      ZS = aa * ZS + bb * Zo; \
      M = MM; \
    } \
  } while (0)
  MERGEG(mA, ZA, EA);
  MERGEG(mB, ZB, EB);
#undef MERGEG
  if (lane < 16) {
    stm[pair][h][0][lane] = mA; stz[pair][h][0][lane] = ZA; ste[pair][h][0][lane] = EA;
    stm[pair][h][1][lane] = mB; stz[pair][h][1][lane] = ZB; ste[pair][h][1][lane] = EB;
  }
  __syncthreads();
  // cross-h merge per rowgroup
#define MERGEH(RG, M, ZS, EV) do { \
    float mo = stm[pair][h ^ 1][RG][l15]; \
    float Zo = stz[pair][h ^ 1][RG][l15]; \
    float Eo = ste[pair][h ^ 1][RG][l15]; \
    float MM = fmaxf(M, mo); \
    float aa = __builtin_amdgcn_exp2f(M - MM); \
    float bb = __builtin_amdgcn_exp2f(mo - MM); \
    EV = aa * (EV - (MM - M) * ZS) + bb * (Eo - (MM - mo) * Zo); \
    ZS = aa * ZS + bb * Zo; \
    M = MM; \
  } while (0)
  MERGEH(0, mA, ZA, EA);
  MERGEH(1, mB, ZB, EB);
#undef MERGEH
  const float invZA = 1.f / ZA;
  const float invZB = 1.f / ZB;
  float kd_acc = 0.f;
  if (h == 0 && g == 0)
    kd_acc = LN2 * ((EA * invZA - __builtin_amdgcn_logf(ZA))
                  + (EB * invZB - __builtin_amdgcn_logf(ZB)));

  // ---- pass C: per-subtile; ey stays in-lane (K=16 PV A-frag), no LDS bounce ----
  f32x4 qA0={0.f,0.f,0.f,0.f}, qA1={0.f,0.f,0.f,0.f}, qA2={0.f,0.f,0.f,0.f}, qA3={0.f,0.f,0.f,0.f};
  f32x4 qB0={0.f,0.f,0.f,0.f}, qB1={0.f,0.f,0.f,0.f}, qB2={0.f,0.f,0.f,0.f}, qB3={0.f,0.f,0.f,0.f};
  float ZyA = 0.f, ZyB = 0.f;
  const float* upA = u + (size_t)(r0 + l15) * SD;
  const float* upB = upA + (size_t)16 * SD;

  for (int tt = ttB; tt < ttB + 32; ++tt) {
    const char* cp = cbbp + (tt * 16 + l15) * 128 + g * 16;
    bf16x8 cf0 = *(const bf16x8*)(cp);
    bf16x8 cf1 = *(const bf16x8*)(cp + 64);
    float4 c2v = *(const float4*)(c2p + tt * 16 + g * 4);
    float4 uA  = *(const float4*)(upA + tt * 16 + g * 4);
    float4 uB  = *(const float4*)(upB + tt * 16 + g * 4);
    // PV B-frags (K=16): B[k=4g+e][dim=dt*16+l15]
    const char* bp = cbtp + l15 * 2048 + tt * 32 + g * 8;
    bf16x4 bt0 = *(const bf16x4*)(bp);
    bf16x4 bt1 = *(const bf16x4*)(bp + 32768);
    bf16x4 bt2 = *(const bf16x4*)(bp + 65536);
    bf16x4 bt3 = *(const bf16x4*)(bp + 98304);
    f32x4 acc0 = {0.f, 0.f, 0.f, 0.f};
    acc0 = __builtin_amdgcn_mfma_f32_16x16x32_bf16(cf0, zfA0, acc0, 0, 0, 0);
    acc0 = __builtin_amdgcn_mfma_f32_16x16x32_bf16(cf1, zfA1, acc0, 0, 0, 0);
    f32x4 acc1 = {0.f, 0.f, 0.f, 0.f};
    acc1 = __builtin_amdgcn_mfma_f32_16x16x32_bf16(cf0, zfB0, acc1, 0, 0, 0);
    acc1 = __builtin_amdgcn_mfma_f32_16x16x32_bf16(cf1, zfB1, acc1, 0, 0, 0);
    float dA0 = fmaf(w22, acc0[0], -(zpA + w2 * c2v.x)) - mA;
    float dA1 = fmaf(w22, acc0[1], -(zpA + w2 * c2v.y)) - mA;
    float dA2 = fmaf(w22, acc0[2], -(zpA + w2 * c2v.z)) - mA;
    float dA3 = fmaf(w22, acc0[3], -(zpA + w2 * c2v.w)) - mA;
    float dB0 = fmaf(w22, acc1[0], -(zpB + w2 * c2v.x)) - mB;
    float dB1 = fmaf(w22, acc1[1], -(zpB + w2 * c2v.y)) - mB;
    float dB2 = fmaf(w22, acc1[2], -(zpB + w2 * c2v.z)) - mB;
    float dB3 = fmaf(w22, acc1[3], -(zpB + w2 * c2v.w)) - mB;
    float eA0 = __builtin_amdgcn_exp2f(dA0), eA1 = __builtin_amdgcn_exp2f(dA1);
    float eA2 = __builtin_amdgcn_exp2f(dA2), eA3 = __builtin_amdgcn_exp2f(dA3);
    float eB0 = __builtin_amdgcn_exp2f(dB0), eB1 = __builtin_amdgcn_exp2f(dB1);
    float eB2 = __builtin_amdgcn_exp2f(dB2), eB3 = __builtin_amdgcn_exp2f(dB3);
    // pav: combine rowgroups, quad-reduce, 4-lane ds_add
    float p0 = eA0 * invZA + eB0 * invZB;
    float p1 = eA1 * invZA + eB1 * invZB;
    float p2 = eA2 * invZA + eB2 * invZB;
    float p3 = eA3 * invZA + eB3 * invZB;
    p0 += __shfl_xor(p0, 1); p1 += __shfl_xor(p1, 1);
    p2 += __shfl_xor(p2, 1); p3 += __shfl_xor(p3, 1);
    p0 += __shfl_xor(p0, 2); p1 += __shfl_xor(p1, 2);
    p2 += __shfl_xor(p2, 2); p3 += __shfl_xor(p3, 2);
    if ((l15 & 3) == 0) {
      float* pp = &pavw[pair][tt * 16 + g * 4];
      atomicAdd(pp + 0, p0); atomicAdd(pp + 1, p1);
      atomicAdd(pp + 2, p2); atomicAdd(pp + 3, p3);
    }
    // gumbel rowgroup A -> in-lane A-frag -> PV (K=16)
    {
      float B0 = fmaf(-LN2, __builtin_amdgcn_logf(uA.x + 1e-10f), 1e-10f);
      float B1 = fmaf(-LN2, __builtin_amdgcn_logf(uA.y + 1e-10f), 1e-10f);
      float B2 = fmaf(-LN2, __builtin_amdgcn_logf(uA.z + 1e-10f), 1e-10f);
      float B3 = fmaf(-LN2, __builtin_amdgcn_logf(uA.w + 1e-10f), 1e-10f);
      float y0 = eA0 * (5.9604645e-8f * __builtin_amdgcn_rcpf(B0));
      float y1 = eA1 * (5.9604645e-8f * __builtin_amdgcn_rcpf(B1));
      float y2 = eA2 * (5.9604645e-8f * __builtin_amdgcn_rcpf(B2));
      float y3 = eA3 * (5.9604645e-8f * __builtin_amdgcn_rcpf(B3));
      ZyA += (y0 + y1) + (y2 + y3);
      bf16x4 ef = mk4(cvtpk(y0, y1), cvtpk(y2, y3));
      qA0 = MFMA16(ef, bt0, qA0);
      qA1 = MFMA16(ef, bt1, qA1);
      qA2 = MFMA16(ef, bt2, qA2);
      qA3 = MFMA16(ef, bt3, qA3);
    }
    // gumbel rowgroup B
    {
      float B0 = fmaf(-LN2, __builtin_amdgcn_logf(uB.x + 1e-10f), 1e-10f);
      float B1 = fmaf(-LN2, __builtin_amdgcn_logf(uB.y + 1e-10f), 1e-10f);
      float B2 = fmaf(-LN2, __builtin_amdgcn_logf(uB.z + 1e-10f), 1e-10f);
      float B3 = fmaf(-LN2, __builtin_amdgcn_logf(uB.w + 1e-10f), 1e-10f);
      float y0 = eB0 * (5.9604645e-8f * __builtin_amdgcn_rcpf(B0));
      float y1 = eB1 * (5.9604645e-8f * __builtin_amdgcn_rcpf(B1));
      float y2 = eB2 * (5.9604645e-8f * __builtin_amdgcn_rcpf(B2));
      float y3 = eB3 * (5.9604645e-8f * __builtin_amdgcn_rcpf(B3));
      ZyB += (y0 + y1) + (y2 + y3);
      bf16x4 ef = mk4(cvtpk(y0, y1), cvtpk(y2, y3));
      qB0 = MFMA16(ef, bt0, qB0);
      qB1 = MFMA16(ef, bt1, qB1);
      qB2 = MFMA16(ef, bt2, qB2);
      qB3 = MFMA16(ef, bt3, qB3);
    }
  }

  // ---- pair merge: Zy + zq partials ----
  ZyA += __shfl_xor(ZyA, 16); ZyA += __shfl_xor(ZyA, 32);
  ZyB += __shfl_xor(ZyB, 16); ZyB += __shfl_xor(ZyB, 32);
  if (lane < 16) { zy2[pair][h][0][lane] = ZyA; zy2[pair][h][1][lane] = ZyB; }
  if (h == 1) {
    char* zq = zqm_s[pair] + lane * 72;
    *(uint2*)(zq +  0) = (uint2){cvtpk(qA0[0], qA0[1]), cvtpk(qA0[2], qA0[3])};
    *(uint2*)(zq +  8) = (uint2){cvtpk(qA1[0], qA1[1]), cvtpk(qA1[2], qA1[3])};
    *(uint2*)(zq + 16) = (uint2){cvtpk(qA2[0], qA2[1]), cvtpk(qA2[2], qA2[3])};
    *(uint2*)(zq + 24) = (uint2){cvtpk(qA3[0], qA3[1]), cvtpk(qA3[2], qA3[3])};
    *(uint2*)(zq + 32) = (uint2){cvtpk(qB0[0], qB0[1]), cvtpk(qB0[2], qB0[3])};
    *(uint2*)(zq + 40) = (uint2){cvtpk(qB1[0], qB1[1]), cvtpk(qB1[2], qB1[3])};
    *(uint2*)(zq + 48) = (uint2){cvtpk(qB2[0], qB2[1]), cvtpk(qB2[2], qB2[3])};
    *(uint2*)(zq + 56) = (uint2){cvtpk(qB3[0], qB3[1]), cvtpk(qB3[2], qB3[3])};
  }
  __syncthreads();

  float kc_acc = 0.f;
  if (h == 0) {
    const char* zq = zqm_s[pair] + lane * 72;
#define FIN1(QD, DT, ZQOFF, IY0, IY1, IY2, IY3, ROWB) do { \
    uint2 v = *(const uint2*)(zq + (ZQOFF) + 8 * (DT)); \
    size_t base = (size_t)((ROWB) + 4 * g) * DIM + (DT) * 16 + l15; \
    float s0 = (QD[0] + bflo(v.x)) * IY0, s1 = (QD[1] + bfhi(v.x)) * IY1; \
    float s2 = (QD[2] + bflo(v.y)) * IY2, s3 = (QD[3] + bfhi(v.y)) * IY3; \
    out[base] = s0; out[base + DIM] = s1; \
    out[base + 2 * DIM] = s2; out[base + 3 * DIM] = s3; \
    float dz0 = z[base] - s0, dz1 = z[base + DIM] - s1; \
    float dz2 = z[base + 2 * DIM] - s2, dz3 = z[base + 3 * DIM] - s3; \
    kc_acc += (dz0 * dz0 + dz1 * dz1) + (dz2 * dz2 + dz3 * dz3); \
  } while (0)
    {
      float iy0 = 1.f / (zy2[pair][0][0][4 * g + 0] + zy2[pair][1][0][4 * g + 0]);
      float iy1 = 1.f / (zy2[pair][0][0][4 * g + 1] + zy2[pair][1][0][4 * g + 1]);
      float iy2 = 1.f / (zy2[pair][0][0][4 * g + 2] + zy2[pair][1][0][4 * g + 2]);
      float iy3 = 1.f / (zy2[pair][0][0][4 * g + 3] + zy2[pair][1][0][4 * g + 3]);
      FIN1(qA0, 0, 0, iy0, iy1, iy2, iy3, r0);
      FIN1(qA1, 1, 0, iy0, iy1, iy2, iy3, r0);
      FIN1(qA2, 2, 0, iy0, iy1, iy2, iy3, r0);
      FIN1(qA3, 3, 0, iy0, iy1, iy2, iy3, r0);
    }
    {
      float iy0 = 1.f / (zy2[pair][0][1][4 * g + 0] + zy2[pair][1][1][4 * g + 0]);
      float iy1 = 1.f / (zy2[pair][0][1][4 * g + 1] + zy2[pair][1][1][4 * g + 1]);
      float iy2 = 1.f / (zy2[pair][0][1][4 * g + 2] + zy2[pair][1][1][4 * g + 2]);
      float iy3 = 1.f / (zy2[pair][0][1][4 * g + 3] + zy2[pair][1][1][4 * g + 3]);
      FIN1(qB0, 0, 32, iy0, iy1, iy2, iy3, r0 + 16);
      FIN1(qB1, 1, 32, iy0, iy1, iy2, iy3, r0 + 16);
      FIN1(qB2, 2, 32, iy0, iy1, iy2, iy3, r0 + 16);
      FIN1(qB3, 3, 32, iy0, iy1, iy2, iy3, r0 + 16);
    }
#undef FIN1
  }
  float kcs = wsum64(kc_acc);
  float kds = wsum64(kd_acc);
  if (lane == 0) wred[wave] = kds + weight * kcs;
  __syncthreads();

  // ---- flush: per-block partials ----
  {
    float s0 = pavw[0][t] + pavw[1][t] + pavw[2][t] + pavw[3][t];
    float s1 = pavw[0][t + 512] + pavw[1][t + 512] + pavw[2][t + 512] + pavw[3][t + 512];
    apart[(size_t)blockIdx.x * 1024 + t]       = s0;
    apart[(size_t)blockIdx.x * 1024 + t + 512] = s1;
    if (t == 0) {
      float L = 0.f;
      #pragma unroll
      for (int w = 0; w < 8; ++w) L += wred[w];
      lpart[blockIdx.x] = L;
    }
  }
}

// ---------------- reduce avg partials: 32 blocks x 16 rows each ----------------
__global__ __launch_bounds__(512) void gvq_red(char* __restrict__ ws) {
  const float* apart = (const float*)(ws + WS_APART);
  float* avgg        = (float*)(ws + WS_AVG);
  int bb = blockIdx.x, t = threadIdx.x;
  float s0 = 0.f, s1 = 0.f;
  #pragma unroll
  for (int r = 0; r < 16; ++r) {
    float2 v = *(const float2*)(apart + (size_t)(bb * 16 + r) * 1024 + t * 2);
    s0 += v.x; s1 += v.y;
  }
  atomicAdd(&avgg[t * 2], s0);
  atomicAdd(&avgg[t * 2 + 1], s1);
}

// ---------------- final: loss + perplexity ----------------
__global__ __launch_bounds__(256) void gvq_final(const char* __restrict__ ws, float* __restrict__ out) {
  const float* avgg  = (const float*)(ws + WS_AVG);
  const float* lpart = (const float*)(ws + WS_LPART);
  int t = threadIdx.x;
  float s = 0.f;
  #pragma unroll
  for (int i = t; i < SD; i += 256) {
    float a = avgg[i] * (1.f / 65536.f);
    s += a * logf(a + 1e-7f);
  }
  float lp = lpart[t] + lpart[t + 256];
  s = wsum64(s); lp = wsum64(lp);
  __shared__ float ws1[4], ws2[4];
  if ((t & 63) == 0) { ws1[t >> 6] = s; ws2[t >> 6] = lp; }
  __syncthreads();
  if (t == 0) {
    float tot = ws1[0] + ws1[1] + ws1[2] + ws1[3];
    float L   = ws2[0] + ws2[1] + ws2[2] + ws2[3];
    out[(size_t)BS * DIM]     = L * (1.f / 65536.f);
    out[(size_t)BS * DIM + 1] = expf(-tot);
  }
}

extern "C" void kernel_launch(void* const* d_in, const int* in_sizes, int n_in,
                              void* d_out, int out_size, void* d_ws, size_t ws_size,
                              hipStream_t stream) {
  (void)in_sizes; (void)n_in; (void)out_size; (void)ws_size;
  const float* z  = (const float*)d_in[0];
  const float* pq = (const float*)d_in[1];
  const float* cb = (const float*)d_in[2];
  const float* u  = (const float*)d_in[3];
  char* ws   = (char*)d_ws;
  float* out = (float*)d_out;
  gvq_prep<<<64, 256, 0, stream>>>(cb, ws);
  gvq_main<<<NBLK, NTHREADS, 0, stream>>>(z, pq, u, ws, out);
  gvq_red<<<32, 512, 0, stream>>>(ws);
  gvq_final<<<1, 256, 0, stream>>>(ws, out);
}

// Round 17
// 158.136 us; speedup vs baseline: 1.1799x; 1.1799x over previous
//
#include <hip/hip_runtime.h>

#define BS 65536
#define DIM 64
#define SD 1024
#define NTHREADS 512
#define NBLK 512          // 8 waves = 4 pairs; pair = 32 rows; halves split 1024 cbs
#define LOG2E 1.44269504f
#define LN2   0.69314718f

// workspace layout (bytes)
#define WS_CBB   0        // [1024][64] bf16 row-major codebook (128 KB)
#define WS_CBT   131072   // [64][1024] bf16 transposed codebook (128 KB)
#define WS_C2    262144   // [1024] f32
#define WS_AVG   266240   // [1024] f32 accumulator (zeroed by prep)
#define WS_APART 270336   // [512][1024] f32 per-block avg partials (2 MB)
#define WS_LPART 2367488  // [512] f32 per-block loss partials

typedef __attribute__((ext_vector_type(8))) short bf16x8;
typedef __attribute__((ext_vector_type(4))) float f32x4;

__device__ __forceinline__ unsigned short f2bf(float f) {
  union { float f; unsigned int u; } v; v.f = f;
  unsigned int r = v.u + 0x7fffu + ((v.u >> 16) & 1u);
  return (unsigned short)(r >> 16);
}
__device__ __forceinline__ unsigned cvtpk(float a, float b) {  // lo=bf16(a), hi=bf16(b)
  unsigned r;
  asm("v_cvt_pk_bf16_f32 %0, %1, %2" : "=v"(r) : "v"(a), "v"(b));
  return r;
}
__device__ __forceinline__ float bflo(unsigned v) {
  union { unsigned u; float f; } x; x.u = v << 16; return x.f;
}
__device__ __forceinline__ float bfhi(unsigned v) {
  union { unsigned u; float f; } x; x.u = v & 0xffff0000u; return x.f;
}
__device__ __forceinline__ float wsum64(float v) {
  #pragma unroll
  for (int m = 1; m < 64; m <<= 1) v += __shfl_xor(v, m);
  return v;
}
__device__ __forceinline__ bf16x8 pack8(float4 a, float4 b) {
  bf16x8 r;
  r[0]=(short)f2bf(a.x); r[1]=(short)f2bf(a.y); r[2]=(short)f2bf(a.z); r[3]=(short)f2bf(a.w);
  r[4]=(short)f2bf(b.x); r[5]=(short)f2bf(b.y); r[6]=(short)f2bf(b.z); r[7]=(short)f2bf(b.w);
  return r;
}

// ---------------- prep: bf16 codebook (row-major + transposed), c2, zero avgg ----------------
__global__ __launch_bounds__(256) void gvq_prep(const float* __restrict__ cb, char* __restrict__ ws) {
  int gid = blockIdx.x * 256 + threadIdx.x;   // 0..16383
  int j = gid >> 4, dg = gid & 15;
  float4 v = *(const float4*)(cb + j * DIM + dg * 4);
  float s = v.x*v.x + v.y*v.y + v.z*v.z + v.w*v.w;
  s += __shfl_xor(s, 1); s += __shfl_xor(s, 2); s += __shfl_xor(s, 4); s += __shfl_xor(s, 8);
  unsigned short b0 = f2bf(v.x), b1 = f2bf(v.y), b2 = f2bf(v.z), b3 = f2bf(v.w);
  uint2 pk;
  pk.x = (unsigned)b0 | ((unsigned)b1 << 16);
  pk.y = (unsigned)b2 | ((unsigned)b3 << 16);
  *(uint2*)(ws + WS_CBB + j * 128 + dg * 8) = pk;
  unsigned short* tb = (unsigned short*)(ws + WS_CBT);
  int d = dg * 4;
  tb[(d + 0) * 1024 + j] = b0; tb[(d + 1) * 1024 + j] = b1;
  tb[(d + 2) * 1024 + j] = b2; tb[(d + 3) * 1024 + j] = b3;
  if (dg == 0) ((float*)(ws + WS_C2))[j] = s;
  if (gid < SD) ((float*)(ws + WS_AVG))[gid] = 0.f;
}

// ---------------- main: 512 blocks x 4 pairs; wave = 32 rows (2 rowgroups) x 512 cbs ----------------
__global__ __launch_bounds__(NTHREADS, 2) void gvq_main(
    const float* __restrict__ z, const float* __restrict__ pq,
    const float* __restrict__ u, char* __restrict__ ws,
    float* __restrict__ out)
{
  __shared__ float pavw[4][1024];        // per-pair avg-prob accumulator
  __shared__ char  eyb_s[8][2560];       // per-wave ey bounce: 32 rows x 80B
  __shared__ char  zqm_s[4][4608];       // per-pair zq partial: 64 lanes x 72B
  __shared__ float stz[4][2][2][16];     // [pair][h][rg][row] Zs halves
  __shared__ float ste[4][2][2][16];     // E1 halves
  __shared__ float zy2[4][2][2][16];     // Zy halves
  __shared__ float wred[8];

  const int t    = threadIdx.x;
  const int lane = t & 63;
  const int wave = t >> 6;
  const int l15  = lane & 15;
  const int g    = lane >> 4;
  const int pair = wave >> 1;
  const int h    = wave & 1;
  const int r0   = blockIdx.x * 128 + pair * 32;
  const int ttB  = h * 32;

  const char*  cbbp = ws + WS_CBB;
  const char*  cbtp = ws + WS_CBT;
  const float* c2p  = (const float*)(ws + WS_C2);
  float* apart = (float*)(ws + WS_APART);
  float* lpart = (float*)(ws + WS_LPART);

  const float weight = 0.5f / fmaxf(pq[0], 1e-10f);
  const float w2  = weight * LOG2E;
  const float w22 = 2.f * w2;

  {
    float* pz = &pavw[0][0];
    #pragma unroll
    for (int i = 0; i < 8; ++i) pz[t + 512 * i] = 0.f;
  }

  // ---- z fragments for both rowgroups + z2 ----
  const float* zrA = z + (size_t)(r0 + l15) * DIM + g * 8;
  const float* zrB = zrA + 16 * DIM;
  float4 a0 = *(const float4*)(zrA),      a1 = *(const float4*)(zrA + 4);
  float4 a2 = *(const float4*)(zrA + 32), a3 = *(const float4*)(zrA + 36);
  float4 b0 = *(const float4*)(zrB),      b1 = *(const float4*)(zrB + 4);
  float4 b2 = *(const float4*)(zrB + 32), b3 = *(const float4*)(zrB + 36);
  bf16x8 zfA0 = pack8(a0, a1), zfA1 = pack8(a2, a3);
  bf16x8 zfB0 = pack8(b0, b1), zfB1 = pack8(b2, b3);
  float zsqA = a0.x*a0.x+a0.y*a0.y+a0.z*a0.z+a0.w*a0.w
             + a1.x*a1.x+a1.y*a1.y+a1.z*a1.z+a1.w*a1.w
             + a2.x*a2.x+a2.y*a2.y+a2.z*a2.z+a2.w*a2.w
             + a3.x*a3.x+a3.y*a3.y+a3.z*a3.z+a3.w*a3.w;
  float zsqB = b0.x*b0.x+b0.y*b0.y+b0.z*b0.z+b0.w*b0.w
             + b1.x*b1.x+b1.y*b1.y+b1.z*b1.z+b1.w*b1.w
             + b2.x*b2.x+b2.y*b2.y+b2.z*b2.z+b2.w*b2.w
             + b3.x*b3.x+b3.y*b3.y+b3.z*b3.z+b3.w*b3.w;
  zsqA += __shfl_xor(zsqA, 16); zsqA += __shfl_xor(zsqA, 32);
  zsqB += __shfl_xor(zsqB, 16); zsqB += __shfl_xor(zsqB, 32);
  const float zpA = w2 * zsqA;
  const float zpB = w2 * zsqB;
  // analytic softmax reference: m_est = -w2*(zsq + 64 - 6.4*sqrt(zsq))
  // fold: d = s - m_est = w22*acc - w2*c2v - KA, KA = zpA + m_est = w2*(6.4*sqrt(zsq) - 64)
  const float KA = w2 * fmaf(6.4f, sqrtf(zsqA), -64.f);
  const float KB = w2 * fmaf(6.4f, sqrtf(zsqB), -64.f);

  // ---- pass AB: Zs, E1 vs analytic reference (no max pass, no serial chains) ----
  float ZsA0 = 0.f, ZsA1 = 0.f, E1A0 = 0.f, E1A1 = 0.f;
  float ZsB0 = 0.f, ZsB1 = 0.f, E1B0 = 0.f, E1B1 = 0.f;
  for (int tt = ttB; tt < ttB + 32; ++tt) {
    const char* cp = cbbp + (tt * 16 + l15) * 128 + g * 16;
    bf16x8 cf0 = *(const bf16x8*)(cp);
    bf16x8 cf1 = *(const bf16x8*)(cp + 64);
    float4 c2v = *(const float4*)(c2p + tt * 16 + g * 4);
    f32x4 acc0 = {0.f, 0.f, 0.f, 0.f};
    acc0 = __builtin_amdgcn_mfma_f32_16x16x32_bf16(cf0, zfA0, acc0, 0, 0, 0);
    acc0 = __builtin_amdgcn_mfma_f32_16x16x32_bf16(cf1, zfA1, acc0, 0, 0, 0);
    f32x4 acc1 = {0.f, 0.f, 0.f, 0.f};
    acc1 = __builtin_amdgcn_mfma_f32_16x16x32_bf16(cf0, zfB0, acc1, 0, 0, 0);
    acc1 = __builtin_amdgcn_mfma_f32_16x16x32_bf16(cf1, zfB1, acc1, 0, 0, 0);
    float tA0 = fmaf(-w2, c2v.x, -KA), tA1 = fmaf(-w2, c2v.y, -KA);
    float tA2 = fmaf(-w2, c2v.z, -KA), tA3 = fmaf(-w2, c2v.w, -KA);
    float dA0 = fmaf(w22, acc0[0], tA0), dA1 = fmaf(w22, acc0[1], tA1);
    float dA2 = fmaf(w22, acc0[2], tA2), dA3 = fmaf(w22, acc0[3], tA3);
    float tB0 = fmaf(-w2, c2v.x, -KB), tB1 = fmaf(-w2, c2v.y, -KB);
    float tB2 = fmaf(-w2, c2v.z, -KB), tB3 = fmaf(-w2, c2v.w, -KB);
    float dB0 = fmaf(w22, acc1[0], tB0), dB1 = fmaf(w22, acc1[1], tB1);
    float dB2 = fmaf(w22, acc1[2], tB2), dB3 = fmaf(w22, acc1[3], tB3);
    float eA0 = __builtin_amdgcn_exp2f(dA0), eA1 = __builtin_amdgcn_exp2f(dA1);
    float eA2 = __builtin_amdgcn_exp2f(dA2), eA3 = __builtin_amdgcn_exp2f(dA3);
    float eB0 = __builtin_amdgcn_exp2f(dB0), eB1 = __builtin_amdgcn_exp2f(dB1);
    float eB2 = __builtin_amdgcn_exp2f(dB2), eB3 = __builtin_amdgcn_exp2f(dB3);
    ZsA0 += eA0 + eA2; ZsA1 += eA1 + eA3;
    E1A0 = fmaf(eA0, dA0, fmaf(eA2, dA2, E1A0));
    E1A1 = fmaf(eA1, dA1, fmaf(eA3, dA3, E1A1));
    ZsB0 += eB0 + eB2; ZsB1 += eB1 + eB3;
    E1B0 = fmaf(eB0, dB0, fmaf(eB2, dB2, E1B0));
    E1B1 = fmaf(eB1, dB1, fmaf(eB3, dB3, E1B1));
  }
  float ZA = ZsA0 + ZsA1, EA = E1A0 + E1A1;
  float ZB = ZsB0 + ZsB1, EB = E1B0 + E1B1;
  // cross-g sum (same row)
  ZA += __shfl_xor(ZA, 16); EA += __shfl_xor(EA, 16);
  ZA += __shfl_xor(ZA, 32); EA += __shfl_xor(EA, 32);
  ZB += __shfl_xor(ZB, 16); EB += __shfl_xor(EB, 16);
  ZB += __shfl_xor(ZB, 32); EB += __shfl_xor(EB, 32);
  if (lane < 16) {
    stz[pair][h][0][lane] = ZA; ste[pair][h][0][lane] = EA;
    stz[pair][h][1][lane] = ZB; ste[pair][h][1][lane] = EB;
  }
  __syncthreads();
  ZA += stz[pair][h ^ 1][0][l15]; EA += ste[pair][h ^ 1][0][l15];
  ZB += stz[pair][h ^ 1][1][l15]; EB += ste[pair][h ^ 1][1][l15];
  const float invZA = 1.f / ZA;
  const float invZB = 1.f / ZB;
  float kd_acc = 0.f;
  if (h == 0 && g == 0)
    kd_acc = LN2 * ((EA * invZA - __builtin_amdgcn_logf(ZA))
                  + (EB * invZB - __builtin_amdgcn_logf(ZB)));

  // ---- pass C: one cf load -> both rowgroups; pav; gumbel ey -> eyb -> K=32 PV ----
  f32x4 qA0={0.f,0.f,0.f,0.f}, qA1={0.f,0.f,0.f,0.f}, qA2={0.f,0.f,0.f,0.f}, qA3={0.f,0.f,0.f,0.f};
  f32x4 qB0={0.f,0.f,0.f,0.f}, qB1={0.f,0.f,0.f,0.f}, qB2={0.f,0.f,0.f,0.f}, qB3={0.f,0.f,0.f,0.f};
  float ZyA = 0.f, ZyB = 0.f;
  const float* upA = u + (size_t)(r0 + l15) * SD;
  const float* upB = upA + (size_t)16 * SD;
  char* eybA = eyb_s[wave] + l15 * 80;
  char* eybB = eyb_s[wave] + (16 + l15) * 80;

  for (int kt = h * 16; kt < h * 16 + 16; ++kt) {
    #pragma unroll
    for (int T = 0; T < 2; ++T) {
      const int tt = kt * 2 + T;
      const char* cp = cbbp + (tt * 16 + l15) * 128 + g * 16;
      bf16x8 cf0 = *(const bf16x8*)(cp);
      bf16x8 cf1 = *(const bf16x8*)(cp + 64);
      float4 c2v = *(const float4*)(c2p + tt * 16 + g * 4);
      float4 uA  = *(const float4*)(upA + tt * 16 + g * 4);
      float4 uB  = *(const float4*)(upB + tt * 16 + g * 4);
      f32x4 acc0 = {0.f, 0.f, 0.f, 0.f};
      acc0 = __builtin_amdgcn_mfma_f32_16x16x32_bf16(cf0, zfA0, acc0, 0, 0, 0);
      acc0 = __builtin_amdgcn_mfma_f32_16x16x32_bf16(cf1, zfA1, acc0, 0, 0, 0);
      f32x4 acc1 = {0.f, 0.f, 0.f, 0.f};
      acc1 = __builtin_amdgcn_mfma_f32_16x16x32_bf16(cf0, zfB0, acc1, 0, 0, 0);
      acc1 = __builtin_amdgcn_mfma_f32_16x16x32_bf16(cf1, zfB1, acc1, 0, 0, 0);
      float dA0 = fmaf(w22, acc0[0], fmaf(-w2, c2v.x, -KA));
      float dA1 = fmaf(w22, acc0[1], fmaf(-w2, c2v.y, -KA));
      float dA2 = fmaf(w22, acc0[2], fmaf(-w2, c2v.z, -KA));
      float dA3 = fmaf(w22, acc0[3], fmaf(-w2, c2v.w, -KA));
      float dB0 = fmaf(w22, acc1[0], fmaf(-w2, c2v.x, -KB));
      float dB1 = fmaf(w22, acc1[1], fmaf(-w2, c2v.y, -KB));
      float dB2 = fmaf(w22, acc1[2], fmaf(-w2, c2v.z, -KB));
      float dB3 = fmaf(w22, acc1[3], fmaf(-w2, c2v.w, -KB));
      float eA0 = __builtin_amdgcn_exp2f(dA0), eA1 = __builtin_amdgcn_exp2f(dA1);
      float eA2 = __builtin_amdgcn_exp2f(dA2), eA3 = __builtin_amdgcn_exp2f(dA3);
      float eB0 = __builtin_amdgcn_exp2f(dB0), eB1 = __builtin_amdgcn_exp2f(dB1);
      float eB2 = __builtin_amdgcn_exp2f(dB2), eB3 = __builtin_amdgcn_exp2f(dB3);
      // pav: combine rowgroups, quad-reduce, 4-lane ds_add
      float p0 = eA0 * invZA + eB0 * invZB;
      float p1 = eA1 * invZA + eB1 * invZB;
      float p2 = eA2 * invZA + eB2 * invZB;
      float p3 = eA3 * invZA + eB3 * invZB;
      p0 += __shfl_xor(p0, 1); p1 += __shfl_xor(p1, 1);
      p2 += __shfl_xor(p2, 1); p3 += __shfl_xor(p3, 1);
      p0 += __shfl_xor(p0, 2); p1 += __shfl_xor(p1, 2);
      p2 += __shfl_xor(p2, 2); p3 += __shfl_xor(p3, 2);
      if ((l15 & 3) == 0) {
        float* pp = &pavw[pair][tt * 16 + g * 4];
        atomicAdd(pp + 0, p0); atomicAdd(pp + 1, p1);
        atomicAdd(pp + 2, p2); atomicAdd(pp + 3, p3);
      }
      // gumbel rowgroup A
      {
        float B0 = fmaf(-LN2, __builtin_amdgcn_logf(uA.x + 1e-10f), 1e-10f);
        float B1 = fmaf(-LN2, __builtin_amdgcn_logf(uA.y + 1e-10f), 1e-10f);
        float B2 = fmaf(-LN2, __builtin_amdgcn_logf(uA.z + 1e-10f), 1e-10f);
        float B3 = fmaf(-LN2, __builtin_amdgcn_logf(uA.w + 1e-10f), 1e-10f);
        float y0 = eA0 * (5.9604645e-8f * __builtin_amdgcn_rcpf(B0));
        float y1 = eA1 * (5.9604645e-8f * __builtin_amdgcn_rcpf(B1));
        float y2 = eA2 * (5.9604645e-8f * __builtin_amdgcn_rcpf(B2));
        float y3 = eA3 * (5.9604645e-8f * __builtin_amdgcn_rcpf(B3));
        ZyA += (y0 + y1) + (y2 + y3);
        uint2 pk;
        pk.x = cvtpk(y0, y1);
        pk.y = cvtpk(y2, y3);
        *(uint2*)(eybA + T * 32 + g * 8) = pk;
      }
      // gumbel rowgroup B
      {
        float B0 = fmaf(-LN2, __builtin_amdgcn_logf(uB.x + 1e-10f), 1e-10f);
        float B1 = fmaf(-LN2, __builtin_amdgcn_logf(uB.y + 1e-10f), 1e-10f);
        float B2 = fmaf(-LN2, __builtin_amdgcn_logf(uB.z + 1e-10f), 1e-10f);
        float B3 = fmaf(-LN2, __builtin_amdgcn_logf(uB.w + 1e-10f), 1e-10f);
        float y0 = eB0 * (5.9604645e-8f * __builtin_amdgcn_rcpf(B0));
        float y1 = eB1 * (5.9604645e-8f * __builtin_amdgcn_rcpf(B1));
        float y2 = eB2 * (5.9604645e-8f * __builtin_amdgcn_rcpf(B2));
        float y3 = eB3 * (5.9604645e-8f * __builtin_amdgcn_rcpf(B3));
        ZyB += (y0 + y1) + (y2 + y3);
        uint2 pk;
        pk.x = cvtpk(y0, y1);
        pk.y = cvtpk(y2, y3);
        *(uint2*)(eybB + T * 32 + g * 8) = pk;
      }
    }
    // PV: shared cbT frags feed both rowgroups (K=32)
    bf16x8 efA = *(const bf16x8*)(eybA + g * 16);
    bf16x8 efB = *(const bf16x8*)(eybB + g * 16);
    const char* bp = cbtp + l15 * 2048 + kt * 64 + g * 16;
    bf16x8 bt0 = *(const bf16x8*)(bp);
    bf16x8 bt1 = *(const bf16x8*)(bp + 32768);
    bf16x8 bt2 = *(const bf16x8*)(bp + 65536);
    bf16x8 bt3 = *(const bf16x8*)(bp + 98304);
    qA0 = __builtin_amdgcn_mfma_f32_16x16x32_bf16(efA, bt0, qA0, 0, 0, 0);
    qA1 = __builtin_amdgcn_mfma_f32_16x16x32_bf16(efA, bt1, qA1, 0, 0, 0);
    qA2 = __builtin_amdgcn_mfma_f32_16x16x32_bf16(efA, bt2, qA2, 0, 0, 0);
    qA3 = __builtin_amdgcn_mfma_f32_16x16x32_bf16(efA, bt3, qA3, 0, 0, 0);
    qB0 = __builtin_amdgcn_mfma_f32_16x16x32_bf16(efB, bt0, qB0, 0, 0, 0);
    qB1 = __builtin_amdgcn_mfma_f32_16x16x32_bf16(efB, bt1, qB1, 0, 0, 0);
    qB2 = __builtin_amdgcn_mfma_f32_16x16x32_bf16(efB, bt2, qB2, 0, 0, 0);
    qB3 = __builtin_amdgcn_mfma_f32_16x16x32_bf16(efB, bt3, qB3, 0, 0, 0);
  }

  // ---- pair merge: Zy + zq partials ----
  ZyA += __shfl_xor(ZyA, 16); ZyA += __shfl_xor(ZyA, 32);
  ZyB += __shfl_xor(ZyB, 16); ZyB += __shfl_xor(ZyB, 32);
  if (lane < 16) { zy2[pair][h][0][lane] = ZyA; zy2[pair][h][1][lane] = ZyB; }
  if (h == 1) {
    char* zq = zqm_s[pair] + lane * 72;
    *(uint2*)(zq +  0) = (uint2){cvtpk(qA0[0], qA0[1]), cvtpk(qA0[2], qA0[3])};
    *(uint2*)(zq +  8) = (uint2){cvtpk(qA1[0], qA1[1]), cvtpk(qA1[2], qA1[3])};
    *(uint2*)(zq + 16) = (uint2){cvtpk(qA2[0], qA2[1]), cvtpk(qA2[2], qA2[3])};
    *(uint2*)(zq + 24) = (uint2){cvtpk(qA3[0], qA3[1]), cvtpk(qA3[2], qA3[3])};
    *(uint2*)(zq + 32) = (uint2){cvtpk(qB0[0], qB0[1]), cvtpk(qB0[2], qB0[3])};
    *(uint2*)(zq + 40) = (uint2){cvtpk(qB1[0], qB1[1]), cvtpk(qB1[2], qB1[3])};
    *(uint2*)(zq + 48) = (uint2){cvtpk(qB2[0], qB2[1]), cvtpk(qB2[2], qB2[3])};
    *(uint2*)(zq + 56) = (uint2){cvtpk(qB3[0], qB3[1]), cvtpk(qB3[2], qB3[3])};
  }
  __syncthreads();

  float kc_acc = 0.f;
  if (h == 0) {
    const char* zq = zqm_s[pair] + lane * 72;
#define FIN1(QD, DT, ZQOFF, IY0, IY1, IY2, IY3, ROWB) do { \
    uint2 v = *(const uint2*)(zq + (ZQOFF) + 8 * (DT)); \
    size_t base = (size_t)((ROWB) + 4 * g) * DIM + (DT) * 16 + l15; \
    float s0 = (QD[0] + bflo(v.x)) * IY0, s1 = (QD[1] + bfhi(v.x)) * IY1; \
    float s2 = (QD[2] + bflo(v.y)) * IY2, s3 = (QD[3] + bfhi(v.y)) * IY3; \
    out[base] = s0; out[base + DIM] = s1; \
    out[base + 2 * DIM] = s2; out[base + 3 * DIM] = s3; \
    float dz0 = z[base] - s0, dz1 = z[base + DIM] - s1; \
    float dz2 = z[base + 2 * DIM] - s2, dz3 = z[base + 3 * DIM] - s3; \
    kc_acc += (dz0 * dz0 + dz1 * dz1) + (dz2 * dz2 + dz3 * dz3); \
  } while (0)
    {
      float iy0 = 1.f / (zy2[pair][0][0][4 * g + 0] + zy2[pair][1][0][4 * g + 0]);
      float iy1 = 1.f / (zy2[pair][0][0][4 * g + 1] + zy2[pair][1][0][4 * g + 1]);
      float iy2 = 1.f / (zy2[pair][0][0][4 * g + 2] + zy2[pair][1][0][4 * g + 2]);
      float iy3 = 1.f / (zy2[pair][0][0][4 * g + 3] + zy2[pair][1][0][4 * g + 3]);
      FIN1(qA0, 0, 0, iy0, iy1, iy2, iy3, r0);
      FIN1(qA1, 1, 0, iy0, iy1, iy2, iy3, r0);
      FIN1(qA2, 2, 0, iy0, iy1, iy2, iy3, r0);
      FIN1(qA3, 3, 0, iy0, iy1, iy2, iy3, r0);
    }
    {
      float iy0 = 1.f / (zy2[pair][0][1][4 * g + 0] + zy2[pair][1][1][4 * g + 0]);
      float iy1 = 1.f / (zy2[pair][0][1][4 * g + 1] + zy2[pair][1][1][4 * g + 1]);
      float iy2 = 1.f / (zy2[pair][0][1][4 * g + 2] + zy2[pair][1][1][4 * g + 2]);
      float iy3 = 1.f / (zy2[pair][0][1][4 * g + 3] + zy2[pair][1][1][4 * g + 3]);
      FIN1(qB0, 0, 32, iy0, iy1, iy2, iy3, r0 + 16);
      FIN1(qB1, 1, 32, iy0, iy1, iy2, iy3, r0 + 16);
      FIN1(qB2, 2, 32, iy0, iy1, iy2, iy3, r0 + 16);
      FIN1(qB3, 3, 32, iy0, iy1, iy2, iy3, r0 + 16);
    }
#undef FIN1
  }
  float kcs = wsum64(kc_acc);
  float kds = wsum64(kd_acc);
  if (lane == 0) wred[wave] = kds + weight * kcs;
  __syncthreads();

  // ---- flush: per-block partials ----
  {
    float s0 = pavw[0][t] + pavw[1][t] + pavw[2][t] + pavw[3][t];
    float s1 = pavw[0][t + 512] + pavw[1][t + 512] + pavw[2][t + 512] + pavw[3][t + 512];
    apart[(size_t)blockIdx.x * 1024 + t]       = s0;
    apart[(size_t)blockIdx.x * 1024 + t + 512] = s1;
    if (t == 0) {
      float L = 0.f;
      #pragma unroll
      for (int w = 0; w < 8; ++w) L += wred[w];
      lpart[blockIdx.x] = L;
    }
  }
}

// ---------------- reduce avg partials: 32 blocks x 16 rows each ----------------
__global__ __launch_bounds__(512) void gvq_red(char* __restrict__ ws) {
  const float* apart = (const float*)(ws + WS_APART);
  float* avgg        = (float*)(ws + WS_AVG);
  int bb = blockIdx.x, t = threadIdx.x;
  float s0 = 0.f, s1 = 0.f;
  #pragma unroll
  for (int r = 0; r < 16; ++r) {
    float2 v = *(const float2*)(apart + (size_t)(bb * 16 + r) * 1024 + t * 2);
    s0 += v.x; s1 += v.y;
  }
  atomicAdd(&avgg[t * 2], s0);
  atomicAdd(&avgg[t * 2 + 1], s1);
}

// ---------------- final: loss + perplexity ----------------
__global__ __launch_bounds__(256) void gvq_final(const char* __restrict__ ws, float* __restrict__ out) {
  const float* avgg  = (const float*)(ws + WS_AVG);
  const float* lpart = (const float*)(ws + WS_LPART);
  int t = threadIdx.x;
  float s = 0.f;
  #pragma unroll
  for (int i = t; i < SD; i += 256) {
    float a = avgg[i] * (1.f / 65536.f);
    s += a * logf(a + 1e-7f);
  }
  float lp = lpart[t] + lpart[t + 256];
  s = wsum64(s); lp = wsum64(lp);
  __shared__ float ws1[4], ws2[4];
  if ((t & 63) == 0) { ws1[t >> 6] = s; ws2[t >> 6] = lp; }
  __syncthreads();
  if (t == 0) {
    float tot = ws1[0] + ws1[1] + ws1[2] + ws1[3];
    float L   = ws2[0] + ws2[1] + ws2[2] + ws2[3];
    out[(size_t)BS * DIM]     = L * (1.f / 65536.f);
    out[(size_t)BS * DIM + 1] = expf(-tot);
  }
}

extern "C" void kernel_launch(void* const* d_in, const int* in_sizes, int n_in,
                              void* d_out, int out_size, void* d_ws, size_t ws_size,
                              hipStream_t stream) {
  (void)in_sizes; (void)n_in; (void)out_size; (void)ws_size;
  const float* z  = (const float*)d_in[0];
  const float* pq = (const float*)d_in[1];
  const float* cb = (const float*)d_in[2];
  const float* u  = (const float*)d_in[3];
  char* ws   = (char*)d_ws;
  float* out = (float*)d_out;
  gvq_prep<<<64, 256, 0, stream>>>(cb, ws);
  gvq_main<<<NBLK, NTHREADS, 0, stream>>>(z, pq, u, ws, out);
  gvq_red<<<32, 512, 0, stream>>>(ws);
  gvq_final<<<1, 256, 0, stream>>>(ws, out);
}

// Round 18
// 156.679 us; speedup vs baseline: 1.1908x; 1.0093x over previous
//
#include <hip/hip_runtime.h>

#define BS 65536
#define DIM 64
#define SD 1024
#define NTHREADS 256
#define NBLK 1024         // 4 waves = 2 pairs; pair = 32 rows; halves split 1024 cbs
#define LOG2E 1.44269504f
#define LN2   0.69314718f

// workspace layout (bytes)
#define WS_CBB   0        // [1024][64] bf16 row-major codebook (128 KB)
#define WS_CBT   131072   // [64][1024] bf16 transposed codebook (128 KB)
#define WS_C2    262144   // [1024] f32
#define WS_AVG   266240   // [1024] f32 accumulator (zeroed by prep)
#define WS_APART 270336   // [1024][1024] f16 per-block avg partials (2 MB)
#define WS_LPART 2367488  // [1024] f32 per-block loss partials

typedef __attribute__((ext_vector_type(8))) short bf16x8;
typedef __attribute__((ext_vector_type(4))) float f32x4;
typedef __attribute__((ext_vector_type(2))) _Float16 f16x2;

__device__ __forceinline__ unsigned short f2bf(float f) {
  union { float f; unsigned int u; } v; v.f = f;
  unsigned int r = v.u + 0x7fffu + ((v.u >> 16) & 1u);
  return (unsigned short)(r >> 16);
}
__device__ __forceinline__ unsigned cvtpk(float a, float b) {  // lo=bf16(a), hi=bf16(b)
  unsigned r;
  asm("v_cvt_pk_bf16_f32 %0, %1, %2" : "=v"(r) : "v"(a), "v"(b));
  return r;
}
__device__ __forceinline__ float bflo(unsigned v) {
  union { unsigned u; float f; } x; x.u = v << 16; return x.f;
}
__device__ __forceinline__ float bfhi(unsigned v) {
  union { unsigned u; float f; } x; x.u = v & 0xffff0000u; return x.f;
}
__device__ __forceinline__ float wsum64(float v) {
  #pragma unroll
  for (int m = 1; m < 64; m <<= 1) v += __shfl_xor(v, m);
  return v;
}
__device__ __forceinline__ bf16x8 pack8(float4 a, float4 b) {
  bf16x8 r;
  r[0]=(short)f2bf(a.x); r[1]=(short)f2bf(a.y); r[2]=(short)f2bf(a.z); r[3]=(short)f2bf(a.w);
  r[4]=(short)f2bf(b.x); r[5]=(short)f2bf(b.y); r[6]=(short)f2bf(b.z); r[7]=(short)f2bf(b.w);
  return r;
}

// ---------------- prep: bf16 codebook (row-major + transposed), c2, zero avgg ----------------
__global__ __launch_bounds__(256) void gvq_prep(const float* __restrict__ cb, char* __restrict__ ws) {
  int gid = blockIdx.x * 256 + threadIdx.x;   // 0..16383
  int j = gid >> 4, dg = gid & 15;
  float4 v = *(const float4*)(cb + j * DIM + dg * 4);
  float s = v.x*v.x + v.y*v.y + v.z*v.z + v.w*v.w;
  s += __shfl_xor(s, 1); s += __shfl_xor(s, 2); s += __shfl_xor(s, 4); s += __shfl_xor(s, 8);
  unsigned short b0 = f2bf(v.x), b1 = f2bf(v.y), b2 = f2bf(v.z), b3 = f2bf(v.w);
  uint2 pk;
  pk.x = (unsigned)b0 | ((unsigned)b1 << 16);
  pk.y = (unsigned)b2 | ((unsigned)b3 << 16);
  *(uint2*)(ws + WS_CBB + j * 128 + dg * 8) = pk;
  unsigned short* tb = (unsigned short*)(ws + WS_CBT);
  int d = dg * 4;
  tb[(d + 0) * 1024 + j] = b0; tb[(d + 1) * 1024 + j] = b1;
  tb[(d + 2) * 1024 + j] = b2; tb[(d + 3) * 1024 + j] = b3;
  if (dg == 0) ((float*)(ws + WS_C2))[j] = s;
  if (gid < SD) ((float*)(ws + WS_AVG))[gid] = 0.f;
}

// ---------------- main: 1024 blocks x 2 pairs; wave = 32 rows (2 rowgroups) x 512 cbs ----------------
__global__ __launch_bounds__(NTHREADS, 2) void gvq_main(
    const float* __restrict__ z, const float* __restrict__ pq,
    const float* __restrict__ u, char* __restrict__ ws,
    float* __restrict__ out)
{
  __shared__ float pavw[2][1024];        // per-pair avg-prob accumulator
  __shared__ char  eyb_s[4][2560];       // per-wave ey bounce: 32 rows x 80B
  __shared__ char  zqm_s[2][4608];       // per-pair zq partial: 64 lanes x 72B
  __shared__ float stz[2][2][2][16];     // [pair][h][rg][row] Zs halves
  __shared__ float ste[2][2][2][16];     // E1 halves
  __shared__ float zy2[2][2][2][16];     // Zy halves
  __shared__ float wred[4];

  const int t    = threadIdx.x;
  const int lane = t & 63;
  const int wave = t >> 6;               // 0..3
  const int l15  = lane & 15;
  const int g    = lane >> 4;
  const int pair = wave >> 1;            // 0..1
  const int h    = wave & 1;
  const int r0   = blockIdx.x * 64 + pair * 32;
  const int ttB  = h * 32;

  const char*  cbbp = ws + WS_CBB;
  const char*  cbtp = ws + WS_CBT;
  const float* c2p  = (const float*)(ws + WS_C2);
  _Float16* apart = (_Float16*)(ws + WS_APART);
  float* lpart = (float*)(ws + WS_LPART);

  const float weight = 0.5f / fmaxf(pq[0], 1e-10f);
  const float w2  = weight * LOG2E;
  const float w22 = 2.f * w2;

  {
    float* pz = &pavw[0][0];
    #pragma unroll
    for (int i = 0; i < 8; ++i) pz[t + 256 * i] = 0.f;
  }

  // ---- z fragments for both rowgroups + z2 ----
  const float* zrA = z + (size_t)(r0 + l15) * DIM + g * 8;
  const float* zrB = zrA + 16 * DIM;
  float4 a0 = *(const float4*)(zrA),      a1 = *(const float4*)(zrA + 4);
  float4 a2 = *(const float4*)(zrA + 32), a3 = *(const float4*)(zrA + 36);
  float4 b0 = *(const float4*)(zrB),      b1 = *(const float4*)(zrB + 4);
  float4 b2 = *(const float4*)(zrB + 32), b3 = *(const float4*)(zrB + 36);
  bf16x8 zfA0 = pack8(a0, a1), zfA1 = pack8(a2, a3);
  bf16x8 zfB0 = pack8(b0, b1), zfB1 = pack8(b2, b3);
  float zsqA = a0.x*a0.x+a0.y*a0.y+a0.z*a0.z+a0.w*a0.w
             + a1.x*a1.x+a1.y*a1.y+a1.z*a1.z+a1.w*a1.w
             + a2.x*a2.x+a2.y*a2.y+a2.z*a2.z+a2.w*a2.w
             + a3.x*a3.x+a3.y*a3.y+a3.z*a3.z+a3.w*a3.w;
  float zsqB = b0.x*b0.x+b0.y*b0.y+b0.z*b0.z+b0.w*b0.w
             + b1.x*b1.x+b1.y*b1.y+b1.z*b1.z+b1.w*b1.w
             + b2.x*b2.x+b2.y*b2.y+b2.z*b2.z+b2.w*b2.w
             + b3.x*b3.x+b3.y*b3.y+b3.z*b3.z+b3.w*b3.w;
  zsqA += __shfl_xor(zsqA, 16); zsqA += __shfl_xor(zsqA, 32);
  zsqB += __shfl_xor(zsqB, 16); zsqB += __shfl_xor(zsqB, 32);
  // analytic softmax reference: m_est = -w2*(zsq + 64 - 6.4*sqrt(zsq))
  const float KA = w2 * fmaf(6.4f, sqrtf(zsqA), -64.f);
  const float KB = w2 * fmaf(6.4f, sqrtf(zsqB), -64.f);

  // ---- pass AB: Zs, E1 vs analytic reference (no max pass, no serial chains) ----
  float ZsA0 = 0.f, ZsA1 = 0.f, E1A0 = 0.f, E1A1 = 0.f;
  float ZsB0 = 0.f, ZsB1 = 0.f, E1B0 = 0.f, E1B1 = 0.f;
  for (int tt = ttB; tt < ttB + 32; ++tt) {
    const char* cp = cbbp + (tt * 16 + l15) * 128 + g * 16;
    bf16x8 cf0 = *(const bf16x8*)(cp);
    bf16x8 cf1 = *(const bf16x8*)(cp + 64);
    float4 c2v = *(const float4*)(c2p + tt * 16 + g * 4);
    f32x4 acc0 = {0.f, 0.f, 0.f, 0.f};
    acc0 = __builtin_amdgcn_mfma_f32_16x16x32_bf16(cf0, zfA0, acc0, 0, 0, 0);
    acc0 = __builtin_amdgcn_mfma_f32_16x16x32_bf16(cf1, zfA1, acc0, 0, 0, 0);
    f32x4 acc1 = {0.f, 0.f, 0.f, 0.f};
    acc1 = __builtin_amdgcn_mfma_f32_16x16x32_bf16(cf0, zfB0, acc1, 0, 0, 0);
    acc1 = __builtin_amdgcn_mfma_f32_16x16x32_bf16(cf1, zfB1, acc1, 0, 0, 0);
    float tA0 = fmaf(-w2, c2v.x, -KA), tA1 = fmaf(-w2, c2v.y, -KA);
    float tA2 = fmaf(-w2, c2v.z, -KA), tA3 = fmaf(-w2, c2v.w, -KA);
    float dA0 = fmaf(w22, acc0[0], tA0), dA1 = fmaf(w22, acc0[1], tA1);
    float dA2 = fmaf(w22, acc0[2], tA2), dA3 = fmaf(w22, acc0[3], tA3);
    float tB0 = fmaf(-w2, c2v.x, -KB), tB1 = fmaf(-w2, c2v.y, -KB);
    float tB2 = fmaf(-w2, c2v.z, -KB), tB3 = fmaf(-w2, c2v.w, -KB);
    float dB0 = fmaf(w22, acc1[0], tB0), dB1 = fmaf(w22, acc1[1], tB1);
    float dB2 = fmaf(w22, acc1[2], tB2), dB3 = fmaf(w22, acc1[3], tB3);
    float eA0 = __builtin_amdgcn_exp2f(dA0), eA1 = __builtin_amdgcn_exp2f(dA1);
    float eA2 = __builtin_amdgcn_exp2f(dA2), eA3 = __builtin_amdgcn_exp2f(dA3);
    float eB0 = __builtin_amdgcn_exp2f(dB0), eB1 = __builtin_amdgcn_exp2f(dB1);
    float eB2 = __builtin_amdgcn_exp2f(dB2), eB3 = __builtin_amdgcn_exp2f(dB3);
    ZsA0 += eA0 + eA2; ZsA1 += eA1 + eA3;
    E1A0 = fmaf(eA0, dA0, fmaf(eA2, dA2, E1A0));
    E1A1 = fmaf(eA1, dA1, fmaf(eA3, dA3, E1A1));
    ZsB0 += eB0 + eB2; ZsB1 += eB1 + eB3;
    E1B0 = fmaf(eB0, dB0, fmaf(eB2, dB2, E1B0));
    E1B1 = fmaf(eB1, dB1, fmaf(eB3, dB3, E1B1));
  }
  float ZA = ZsA0 + ZsA1, EA = E1A0 + E1A1;
  float ZB = ZsB0 + ZsB1, EB = E1B0 + E1B1;
  ZA += __shfl_xor(ZA, 16); EA += __shfl_xor(EA, 16);
  ZA += __shfl_xor(ZA, 32); EA += __shfl_xor(EA, 32);
  ZB += __shfl_xor(ZB, 16); EB += __shfl_xor(EB, 16);
  ZB += __shfl_xor(ZB, 32); EB += __shfl_xor(EB, 32);
  if (lane < 16) {
    stz[pair][h][0][lane] = ZA; ste[pair][h][0][lane] = EA;
    stz[pair][h][1][lane] = ZB; ste[pair][h][1][lane] = EB;
  }
  __syncthreads();
  ZA += stz[pair][h ^ 1][0][l15]; EA += ste[pair][h ^ 1][0][l15];
  ZB += stz[pair][h ^ 1][1][l15]; EB += ste[pair][h ^ 1][1][l15];
  const float invZA = 1.f / ZA;
  const float invZB = 1.f / ZB;
  float kd_acc = 0.f;
  if (h == 0 && g == 0)
    kd_acc = LN2 * ((EA * invZA - __builtin_amdgcn_logf(ZA))
                  + (EB * invZB - __builtin_amdgcn_logf(ZB)));

  // ---- pass C: one cf load -> both rowgroups; pav; gumbel ey -> eyb -> K=32 PV ----
  f32x4 qA0={0.f,0.f,0.f,0.f}, qA1={0.f,0.f,0.f,0.f}, qA2={0.f,0.f,0.f,0.f}, qA3={0.f,0.f,0.f,0.f};
  f32x4 qB0={0.f,0.f,0.f,0.f}, qB1={0.f,0.f,0.f,0.f}, qB2={0.f,0.f,0.f,0.f}, qB3={0.f,0.f,0.f,0.f};
  float ZyA = 0.f, ZyB = 0.f;
  const float* upA = u + (size_t)(r0 + l15) * SD;
  const float* upB = upA + (size_t)16 * SD;
  char* eybA = eyb_s[wave] + l15 * 80;
  char* eybB = eyb_s[wave] + (16 + l15) * 80;

  for (int kt = h * 16; kt < h * 16 + 16; ++kt) {
    #pragma unroll
    for (int T = 0; T < 2; ++T) {
      const int tt = kt * 2 + T;
      const char* cp = cbbp + (tt * 16 + l15) * 128 + g * 16;
      bf16x8 cf0 = *(const bf16x8*)(cp);
      bf16x8 cf1 = *(const bf16x8*)(cp + 64);
      float4 c2v = *(const float4*)(c2p + tt * 16 + g * 4);
      float4 uA  = *(const float4*)(upA + tt * 16 + g * 4);
      float4 uB  = *(const float4*)(upB + tt * 16 + g * 4);
      f32x4 acc0 = {0.f, 0.f, 0.f, 0.f};
      acc0 = __builtin_amdgcn_mfma_f32_16x16x32_bf16(cf0, zfA0, acc0, 0, 0, 0);
      acc0 = __builtin_amdgcn_mfma_f32_16x16x32_bf16(cf1, zfA1, acc0, 0, 0, 0);
      f32x4 acc1 = {0.f, 0.f, 0.f, 0.f};
      acc1 = __builtin_amdgcn_mfma_f32_16x16x32_bf16(cf0, zfB0, acc1, 0, 0, 0);
      acc1 = __builtin_amdgcn_mfma_f32_16x16x32_bf16(cf1, zfB1, acc1, 0, 0, 0);
      float dA0 = fmaf(w22, acc0[0], fmaf(-w2, c2v.x, -KA));
      float dA1 = fmaf(w22, acc0[1], fmaf(-w2, c2v.y, -KA));
      float dA2 = fmaf(w22, acc0[2], fmaf(-w2, c2v.z, -KA));
      float dA3 = fmaf(w22, acc0[3], fmaf(-w2, c2v.w, -KA));
      float dB0 = fmaf(w22, acc1[0], fmaf(-w2, c2v.x, -KB));
      float dB1 = fmaf(w22, acc1[1], fmaf(-w2, c2v.y, -KB));
      float dB2 = fmaf(w22, acc1[2], fmaf(-w2, c2v.z, -KB));
      float dB3 = fmaf(w22, acc1[3], fmaf(-w2, c2v.w, -KB));
      float eA0 = __builtin_amdgcn_exp2f(dA0), eA1 = __builtin_amdgcn_exp2f(dA1);
      float eA2 = __builtin_amdgcn_exp2f(dA2), eA3 = __builtin_amdgcn_exp2f(dA3);
      float eB0 = __builtin_amdgcn_exp2f(dB0), eB1 = __builtin_amdgcn_exp2f(dB1);
      float eB2 = __builtin_amdgcn_exp2f(dB2), eB3 = __builtin_amdgcn_exp2f(dB3);
      // pav: combine rowgroups, quad-reduce, 4-lane ds_add
      float p0 = eA0 * invZA + eB0 * invZB;
      float p1 = eA1 * invZA + eB1 * invZB;
      float p2 = eA2 * invZA + eB2 * invZB;
      float p3 = eA3 * invZA + eB3 * invZB;
      p0 += __shfl_xor(p0, 1); p1 += __shfl_xor(p1, 1);
      p2 += __shfl_xor(p2, 1); p3 += __shfl_xor(p3, 1);
      p0 += __shfl_xor(p0, 2); p1 += __shfl_xor(p1, 2);
      p2 += __shfl_xor(p2, 2); p3 += __shfl_xor(p3, 2);
      if ((l15 & 3) == 0) {
        float* pp = &pavw[pair][tt * 16 + g * 4];
        atomicAdd(pp + 0, p0); atomicAdd(pp + 1, p1);
        atomicAdd(pp + 2, p2); atomicAdd(pp + 3, p3);
      }
      // gumbel rowgroup A
      {
        float B0 = fmaf(-LN2, __builtin_amdgcn_logf(uA.x + 1e-10f), 1e-10f);
        float B1 = fmaf(-LN2, __builtin_amdgcn_logf(uA.y + 1e-10f), 1e-10f);
        float B2 = fmaf(-LN2, __builtin_amdgcn_logf(uA.z + 1e-10f), 1e-10f);
        float B3 = fmaf(-LN2, __builtin_amdgcn_logf(uA.w + 1e-10f), 1e-10f);
        float y0 = eA0 * (5.9604645e-8f * __builtin_amdgcn_rcpf(B0));
        float y1 = eA1 * (5.9604645e-8f * __builtin_amdgcn_rcpf(B1));
        float y2 = eA2 * (5.9604645e-8f * __builtin_amdgcn_rcpf(B2));
        float y3 = eA3 * (5.9604645e-8f * __builtin_amdgcn_rcpf(B3));
        ZyA += (y0 + y1) + (y2 + y3);
        uint2 pk;
        pk.x = cvtpk(y0, y1);
        pk.y = cvtpk(y2, y3);
        *(uint2*)(eybA + T * 32 + g * 8) = pk;
      }
      // gumbel rowgroup B
      {
        float B0 = fmaf(-LN2, __builtin_amdgcn_logf(uB.x + 1e-10f), 1e-10f);
        float B1 = fmaf(-LN2, __builtin_amdgcn_logf(uB.y + 1e-10f), 1e-10f);
        float B2 = fmaf(-LN2, __builtin_amdgcn_logf(uB.z + 1e-10f), 1e-10f);
        float B3 = fmaf(-LN2, __builtin_amdgcn_logf(uB.w + 1e-10f), 1e-10f);
        float y0 = eB0 * (5.9604645e-8f * __builtin_amdgcn_rcpf(B0));
        float y1 = eB1 * (5.9604645e-8f * __builtin_amdgcn_rcpf(B1));
        float y2 = eB2 * (5.9604645e-8f * __builtin_amdgcn_rcpf(B2));
        float y3 = eB3 * (5.9604645e-8f * __builtin_amdgcn_rcpf(B3));
        ZyB += (y0 + y1) + (y2 + y3);
        uint2 pk;
        pk.x = cvtpk(y0, y1);
        pk.y = cvtpk(y2, y3);
        *(uint2*)(eybB + T * 32 + g * 8) = pk;
      }
    }
    // PV: shared cbT frags feed both rowgroups (K=32)
    bf16x8 efA = *(const bf16x8*)(eybA + g * 16);
    bf16x8 efB = *(const bf16x8*)(eybB + g * 16);
    const char* bp = cbtp + l15 * 2048 + kt * 64 + g * 16;
    bf16x8 bt0 = *(const bf16x8*)(bp);
    bf16x8 bt1 = *(const bf16x8*)(bp + 32768);
    bf16x8 bt2 = *(const bf16x8*)(bp + 65536);
    bf16x8 bt3 = *(const bf16x8*)(bp + 98304);
    qA0 = __builtin_amdgcn_mfma_f32_16x16x32_bf16(efA, bt0, qA0, 0, 0, 0);
    qA1 = __builtin_amdgcn_mfma_f32_16x16x32_bf16(efA, bt1, qA1, 0, 0, 0);
    qA2 = __builtin_amdgcn_mfma_f32_16x16x32_bf16(efA, bt2, qA2, 0, 0, 0);
    qA3 = __builtin_amdgcn_mfma_f32_16x16x32_bf16(efA, bt3, qA3, 0, 0, 0);
    qB0 = __builtin_amdgcn_mfma_f32_16x16x32_bf16(efB, bt0, qB0, 0, 0, 0);
    qB1 = __builtin_amdgcn_mfma_f32_16x16x32_bf16(efB, bt1, qB1, 0, 0, 0);
    qB2 = __builtin_amdgcn_mfma_f32_16x16x32_bf16(efB, bt2, qB2, 0, 0, 0);
    qB3 = __builtin_amdgcn_mfma_f32_16x16x32_bf16(efB, bt3, qB3, 0, 0, 0);
  }

  // ---- pair merge: Zy + zq partials ----
  ZyA += __shfl_xor(ZyA, 16); ZyA += __shfl_xor(ZyA, 32);
  ZyB += __shfl_xor(ZyB, 16); ZyB += __shfl_xor(ZyB, 32);
  if (lane < 16) { zy2[pair][h][0][lane] = ZyA; zy2[pair][h][1][lane] = ZyB; }
  if (h == 1) {
    char* zq = zqm_s[pair] + lane * 72;
    *(uint2*)(zq +  0) = (uint2){cvtpk(qA0[0], qA0[1]), cvtpk(qA0[2], qA0[3])};
    *(uint2*)(zq +  8) = (uint2){cvtpk(qA1[0], qA1[1]), cvtpk(qA1[2], qA1[3])};
    *(uint2*)(zq + 16) = (uint2){cvtpk(qA2[0], qA2[1]), cvtpk(qA2[2], qA2[3])};
    *(uint2*)(zq + 24) = (uint2){cvtpk(qA3[0], qA3[1]), cvtpk(qA3[2], qA3[3])};
    *(uint2*)(zq + 32) = (uint2){cvtpk(qB0[0], qB0[1]), cvtpk(qB0[2], qB0[3])};
    *(uint2*)(zq + 40) = (uint2){cvtpk(qB1[0], qB1[1]), cvtpk(qB1[2], qB1[3])};
    *(uint2*)(zq + 48) = (uint2){cvtpk(qB2[0], qB2[1]), cvtpk(qB2[2], qB2[3])};
    *(uint2*)(zq + 56) = (uint2){cvtpk(qB3[0], qB3[1]), cvtpk(qB3[2], qB3[3])};
  }
  __syncthreads();

  float kc_acc = 0.f;
  if (h == 0) {
    const char* zq = zqm_s[pair] + lane * 72;
#define FIN1(QD, DT, ZQOFF, IY0, IY1, IY2, IY3, ROWB) do { \
    uint2 v = *(const uint2*)(zq + (ZQOFF) + 8 * (DT)); \
    size_t base = (size_t)((ROWB) + 4 * g) * DIM + (DT) * 16 + l15; \
    float s0 = (QD[0] + bflo(v.x)) * IY0, s1 = (QD[1] + bfhi(v.x)) * IY1; \
    float s2 = (QD[2] + bflo(v.y)) * IY2, s3 = (QD[3] + bfhi(v.y)) * IY3; \
    out[base] = s0; out[base + DIM] = s1; \
    out[base + 2 * DIM] = s2; out[base + 3 * DIM] = s3; \
    float dz0 = z[base] - s0, dz1 = z[base + DIM] - s1; \
    float dz2 = z[base + 2 * DIM] - s2, dz3 = z[base + 3 * DIM] - s3; \
    kc_acc += (dz0 * dz0 + dz1 * dz1) + (dz2 * dz2 + dz3 * dz3); \
  } while (0)
    {
      float iy0 = 1.f / (zy2[pair][0][0][4 * g + 0] + zy2[pair][1][0][4 * g + 0]);
      float iy1 = 1.f / (zy2[pair][0][0][4 * g + 1] + zy2[pair][1][0][4 * g + 1]);
      float iy2 = 1.f / (zy2[pair][0][0][4 * g + 2] + zy2[pair][1][0][4 * g + 2]);
      float iy3 = 1.f / (zy2[pair][0][0][4 * g + 3] + zy2[pair][1][0][4 * g + 3]);
      FIN1(qA0, 0, 0, iy0, iy1, iy2, iy3, r0);
      FIN1(qA1, 1, 0, iy0, iy1, iy2, iy3, r0);
      FIN1(qA2, 2, 0, iy0, iy1, iy2, iy3, r0);
      FIN1(qA3, 3, 0, iy0, iy1, iy2, iy3, r0);
    }
    {
      float iy0 = 1.f / (zy2[pair][0][1][4 * g + 0] + zy2[pair][1][1][4 * g + 0]);
      float iy1 = 1.f / (zy2[pair][0][1][4 * g + 1] + zy2[pair][1][1][4 * g + 1]);
      float iy2 = 1.f / (zy2[pair][0][1][4 * g + 2] + zy2[pair][1][1][4 * g + 2]);
      float iy3 = 1.f / (zy2[pair][0][1][4 * g + 3] + zy2[pair][1][1][4 * g + 3]);
      FIN1(qB0, 0, 32, iy0, iy1, iy2, iy3, r0 + 16);
      FIN1(qB1, 1, 32, iy0, iy1, iy2, iy3, r0 + 16);
      FIN1(qB2, 2, 32, iy0, iy1, iy2, iy3, r0 + 16);
      FIN1(qB3, 3, 32, iy0, iy1, iy2, iy3, r0 + 16);
    }
#undef FIN1
  }
  float kcs = wsum64(kc_acc);
  float kds = wsum64(kd_acc);
  if (lane == 0) wred[wave] = kds + weight * kcs;
  __syncthreads();

  // ---- flush: per-block partials (f16) ----
  {
    #pragma unroll
    for (int k = 0; k < 4; ++k) {
      int cc = t + 256 * k;
      apart[(size_t)blockIdx.x * 1024 + cc] = (_Float16)(pavw[0][cc] + pavw[1][cc]);
    }
    if (t == 0)
      lpart[blockIdx.x] = wred[0] + wred[1] + wred[2] + wred[3];
  }
}

// ---------------- reduce avg partials: 32 blocks x 32 rows each ----------------
__global__ __launch_bounds__(512) void gvq_red(char* __restrict__ ws) {
  const _Float16* apart = (const _Float16*)(ws + WS_APART);
  float* avgg           = (float*)(ws + WS_AVG);
  int bb = blockIdx.x, t = threadIdx.x;
  float s0 = 0.f, s1 = 0.f;
  #pragma unroll
  for (int r = 0; r < 32; ++r) {
    f16x2 v = *(const f16x2*)(apart + (size_t)(bb * 32 + r) * 1024 + t * 2);
    s0 += (float)v[0]; s1 += (float)v[1];
  }
  atomicAdd(&avgg[t * 2], s0);
  atomicAdd(&avgg[t * 2 + 1], s1);
}

// ---------------- final: loss + perplexity ----------------
__global__ __launch_bounds__(256) void gvq_final(const char* __restrict__ ws, float* __restrict__ out) {
  const float* avgg  = (const float*)(ws + WS_AVG);
  const float* lpart = (const float*)(ws + WS_LPART);
  int t = threadIdx.x;
  float s = 0.f;
  #pragma unroll
  for (int i = t; i < SD; i += 256) {
    float a = avgg[i] * (1.f / 65536.f);
    s += a * logf(a + 1e-7f);
  }
  float lp = lpart[t] + lpart[t + 256] + lpart[t + 512] + lpart[t + 768];
  s = wsum64(s); lp = wsum64(lp);
  __shared__ float ws1[4], ws2[4];
  if ((t & 63) == 0) { ws1[t >> 6] = s; ws2[t >> 6] = lp; }
  __syncthreads();
  if (t == 0) {
    float tot = ws1[0] + ws1[1] + ws1[2] + ws1[3];
    float L   = ws2[0] + ws2[1] + ws2[2] + ws2[3];
    out[(size_t)BS * DIM]     = L * (1.f / 65536.f);
    out[(size_t)BS * DIM + 1] = expf(-tot);
  }
}

extern "C" void kernel_launch(void* const* d_in, const int* in_sizes, int n_in,
                              void* d_out, int out_size, void* d_ws, size_t ws_size,
                              hipStream_t stream) {
  (void)in_sizes; (void)n_in; (void)out_size; (void)ws_size;
  const float* z  = (const float*)d_in[0];
  const float* pq = (const float*)d_in[1];
  const float* cb = (const float*)d_in[2];
  const float* u  = (const float*)d_in[3];
  char* ws   = (char*)d_ws;
  float* out = (float*)d_out;
  gvq_prep<<<64, 256, 0, stream>>>(cb, ws);
  gvq_main<<<NBLK, NTHREADS, 0, stream>>>(z, pq, u, ws, out);
  gvq_red<<<32, 512, 0, stream>>>(ws);
  gvq_final<<<1, 256, 0, stream>>>(ws, out);
}